// Round 1
// baseline (771.815 us; speedup 1.0000x reference)
//
#include <hip/hip_runtime.h>
#include <cmath>

#define V_SIZE 50000
#define B_SIZE 256
#define D_SIZE 64
#define NCTX 8                    // 2N context rows
#define NROWS (NCTX * B_SIZE)     // 2048 one-hot rows
#define VTILES ((V_SIZE + 255) / 256)   // 196 v-tiles of 256 threads

// ---------------------------------------------------------------------------
// K1: extract one-hot indices. One block per (i,b) row; 409.6 MB streamed,
// float4-coalesced. Exactly one element per row is 1.0f. HBM-bound floor
// (~65 us) — this is the structural floor of the whole pipeline.
// ---------------------------------------------------------------------------
__global__ __launch_bounds__(256) void k_find_ids(const float* __restrict__ in,
                                                  int* __restrict__ ids) {
    const int row = blockIdx.x;  // [0, 2048)
    const float4* r4 = (const float4*)(in + (size_t)row * V_SIZE);
    for (int j = threadIdx.x; j < V_SIZE / 4; j += 256) {
        float4 x = r4[j];
        if (x.x > 0.5f) ids[row] = 4 * j;
        if (x.y > 0.5f) ids[row] = 4 * j + 1;
        if (x.z > 0.5f) ids[row] = 4 * j + 2;
        if (x.w > 0.5f) ids[row] = 4 * j + 3;
    }
}

// ---------------------------------------------------------------------------
// K2: h[b][d] = b1[d] + (1/8) * sum_i w1[d*V + ids[i,b]].
// One block per b (1 wave, thread = d). 2048-column gather, ~8.4 MB of lines.
// ---------------------------------------------------------------------------
__global__ __launch_bounds__(64) void k_h(const int* __restrict__ ids,
                                          const float* __restrict__ w1,
                                          const float* __restrict__ b1,
                                          float* __restrict__ h) {
    const int b = blockIdx.x;
    const int d = threadIdx.x;
    float acc = 0.0f;
#pragma unroll
    for (int i = 0; i < NCTX; ++i) {
        int id = ids[i * B_SIZE + b];          // wave-uniform -> scalar load
        acc += w1[(size_t)d * V_SIZE + id];
    }
    h[b * D_SIZE + d] = acc * 0.125f + b1[d];
}

// ---------------------------------------------------------------------------
// Shared dot: thread owns one v (w2 row in 16 float4 VGPRs); h row address is
// wave-uniform -> compiler scalarizes to s_load (one L1 line per wave).
// ---------------------------------------------------------------------------
__device__ __forceinline__ float dot64(const float4* __restrict__ hb,
                                       const float4 w2r[16]) {
    float a0 = 0.f, a1 = 0.f, a2 = 0.f, a3 = 0.f;
#pragma unroll
    for (int j = 0; j < 16; j += 4) {
        float4 h0 = hb[j], h1 = hb[j + 1], h2 = hb[j + 2], h3 = hb[j + 3];
        a0 += w2r[j].x * h0.x + w2r[j].y * h0.y + w2r[j].z * h0.z + w2r[j].w * h0.w;
        a1 += w2r[j + 1].x * h1.x + w2r[j + 1].y * h1.y + w2r[j + 1].z * h1.z + w2r[j + 1].w * h1.w;
        a2 += w2r[j + 2].x * h2.x + w2r[j + 2].y * h2.y + w2r[j + 2].z * h2.z + w2r[j + 2].w * h2.w;
        a3 += w2r[j + 3].x * h3.x + w2r[j + 3].y * h3.y + w2r[j + 3].z * h3.z + w2r[j + 3].w * h3.w;
    }
    return (a0 + a1) + (a2 + a3);
}

// ---------------------------------------------------------------------------
// Pass 1: stats WITHOUT materializing logits. Block = (v-tile of 256, b-quad
// of 64). Per bi: compute logit in-register, 64-lane max-butterfly, exp,
// sum-butterfly -> per-wave (m,s) -> LDS -> per-tile (m,s) per b.
// Invalid lanes (v >= 50000, tail tile) use x=-1e30 -> exp contributes 0.
// ZERO traffic on the 51.2 MB out buffer (was: write + read + RMW = 204.8 MB
// across the old K3/K4a/K4c).
// ---------------------------------------------------------------------------
__global__ __launch_bounds__(256) void k_stats_fused(const float* __restrict__ h,
                                                     const float* __restrict__ w2,
                                                     const float* __restrict__ b2,
                                                     float2* __restrict__ partial) {
    const int v = blockIdx.x * 256 + threadIdx.x;
    const bool valid = v < V_SIZE;

    float4 w2r[16];
    if (valid) {
        const float4* wrow = (const float4*)(w2 + (size_t)v * D_SIZE);
#pragma unroll
        for (int j = 0; j < 16; ++j) w2r[j] = wrow[j];
    } else {
#pragma unroll
        for (int j = 0; j < 16; ++j) w2r[j] = make_float4(0.f, 0.f, 0.f, 0.f);
    }
    const float bias = valid ? b2[v] : 0.0f;

    __shared__ float sm[64][4], ss[64][4];
    const int wid = threadIdx.x >> 6, lane = threadIdx.x & 63;
    const int b0 = blockIdx.y * 64;

    for (int bi = 0; bi < 64; ++bi) {
        const float4* hb = (const float4*)(h + (size_t)(b0 + bi) * D_SIZE);
        float x = valid ? dot64(hb, w2r) + bias : -1e30f;

        // max over the wave's 64 v-lanes (all lanes end with the max)
        float m = x;
#pragma unroll
        for (int off = 1; off < 64; off <<= 1)
            m = fmaxf(m, __shfl_xor(m, off, 64));
        // sum of exp(x - m); invalid lanes: exp(-1e30 - m) == 0
        float s = __expf(x - m);
#pragma unroll
        for (int off = 1; off < 64; off <<= 1)
            s += __shfl_xor(s, off, 64);

        if (lane == 0) { sm[bi][wid] = m; ss[bi][wid] = s; }
    }
    __syncthreads();

    // threads 0..63: merge the 4 wave-partials for bi = tid.
    // Fully-invalid waves stored (m=-1e30, s=64): merges to +0 contribution.
    if (threadIdx.x < 64) {
        const int bi = threadIdx.x;
        float M = sm[bi][0], S = ss[bi][0];
#pragma unroll
        for (int w = 1; w < 4; ++w) {
            float M2 = fmaxf(M, sm[bi][w]);
            S = S * __expf(M - M2) + ss[bi][w] * __expf(sm[bi][w] - M2);
            M = M2;
        }
        // layout [tile][b]: coalesced for k_combine
        partial[(size_t)blockIdx.x * B_SIZE + (b0 + bi)] = make_float2(M, S);
    }
}

// ---------------------------------------------------------------------------
// Combine 196 tile-partials per b -> logZ[b]. One block, thread = b; loads
// are coalesced (lane b reads partial[t*256 + b]), ~400 KB, L2-resident.
// ---------------------------------------------------------------------------
__global__ __launch_bounds__(256) void k_combine(const float2* __restrict__ partial,
                                                 float* __restrict__ logZ) {
    const int b = threadIdx.x;
    float2 p = partial[b];
    float M = p.x, S = p.y;
    for (int t = 1; t < VTILES; ++t) {
        float2 q = partial[(size_t)t * B_SIZE + b];
        float M2 = fmaxf(M, q.x);
        S = S * __expf(M - M2) + q.y * __expf(q.x - M2);
        M = M2;
    }
    logZ[b] = M + __logf(S);
}

// ---------------------------------------------------------------------------
// Pass 2: recompute the dot (w2 is L3-hot after pass 1; 10 us of VALU) and
// write the FINAL value once: out = dot + b2[v] - logZ[b]. 51.2 MB written,
// nothing read back.
// ---------------------------------------------------------------------------
__global__ __launch_bounds__(256) void k_write(const float* __restrict__ h,
                                               const float* __restrict__ w2,
                                               const float* __restrict__ b2,
                                               const float* __restrict__ logZ,
                                               float* __restrict__ out) {
    const int v = blockIdx.x * 256 + threadIdx.x;
    if (v >= V_SIZE) return;

    float4 w2r[16];
    const float4* wrow = (const float4*)(w2 + (size_t)v * D_SIZE);
#pragma unroll
    for (int j = 0; j < 16; ++j) w2r[j] = wrow[j];
    const float bias = b2[v];

    const int b0 = blockIdx.y * 64;
    for (int bi = 0; bi < 64; ++bi) {
        const int b = b0 + bi;
        const float lz = logZ[b];   // wave-uniform -> scalar load
        const float4* hb = (const float4*)(h + (size_t)b * D_SIZE);
        out[(size_t)b * V_SIZE + v] = dot64(hb, w2r) + bias - lz;
    }
}

// ---------------------------------------------------------------------------
extern "C" void kernel_launch(void* const* d_in, const int* in_sizes, int n_in,
                              void* d_out, int out_size, void* d_ws, size_t ws_size,
                              hipStream_t stream) {
    const float* in = (const float*)d_in[0];   // [8, 256, 50000] one-hot
    const float* w1 = (const float*)d_in[1];   // [64, 50000]
    const float* b1 = (const float*)d_in[2];   // [64]
    const float* w2 = (const float*)d_in[3];   // [50000, 64]
    const float* b2 = (const float*)d_in[4];   // [50000]
    float* out = (float*)d_out;                // [256, 50000]

    // workspace: ids 8 KB | h 64 KB | logZ 1 KB | partial 196*256*8 = 401 KB
    char* ws = (char*)d_ws;
    int*    ids     = (int*)ws;                               // 8 KB
    float*  h       = (float*)(ws + 8192);                    // 64 KB
    float*  logZ    = (float*)(ws + 8192 + 65536);            // 1 KB
    float2* partial = (float2*)(ws + 8192 + 65536 + 4096);    // 401 KB

    k_find_ids<<<NROWS, 256, 0, stream>>>(in, ids);
    k_h<<<B_SIZE, 64, 0, stream>>>(ids, w1, b1, h);
    k_stats_fused<<<dim3(VTILES, 4), 256, 0, stream>>>(h, w2, b2, partial);
    k_combine<<<1, 256, 0, stream>>>(partial, logZ);
    k_write<<<dim3(VTILES, 4), 256, 0, stream>>>(h, w2, b2, logZ, out);
}